// Round 1
// baseline (1628.145 us; speedup 1.0000x reference)
//
#include <hip/hip_runtime.h>

#define BN 16384
#define DD 16
#define KNN 25
#define NBINS 2048
#define COLLCAP 256

// ---------------- recon: mean((outputs-targets)^2) partials ----------------
__global__ void recon_kernel(const float* __restrict__ o, const float* __restrict__ t,
                             float* __restrict__ part) {
    __shared__ float red[256];
    int tid = threadIdx.x;
    int idx = blockIdx.x * 256 + tid;
    float s = 0.f;
    for (int i = idx; i < BN * DD; i += 256 * 256) {
        float d = o[i] - t[i];
        s += d * d;
    }
    red[tid] = s;
    __syncthreads();
    for (int off = 128; off > 0; off >>= 1) {
        if (tid < off) red[tid] += red[tid + off];
        __syncthreads();
    }
    if (tid == 0) part[blockIdx.x] = red[0];
}

// ---------------- per-row: 25-NN + top-eigvec of 2 covariances ----------------
__global__ __launch_bounds__(256) void tsa_kernel(const float* __restrict__ latent,
                                                  const float* __restrict__ raw,
                                                  float* __restrict__ tsa) {
    const int row = blockIdx.x;
    const int tid = threadIdx.x;

    __shared__ float d2buf[BN];        // 64 KB
    __shared__ unsigned hist[NBINS];   // 8 KB
    __shared__ unsigned scanA[256];
    __shared__ float q[DD];
    __shared__ float collV[COLLCAP];
    __shared__ int   collI[COLLCAP];
    __shared__ int   collCnt;
    __shared__ int   binB;
    __shared__ int   nbr[KNN];
    __shared__ float pts[KNN][DD];
    __shared__ float mean_s[DD];
    __shared__ float Cm[256];
    __shared__ float C2m[256];
    __shared__ float vv[DD], ww[DD];
    __shared__ float sc[4];
    __shared__ float uv[2][DD];

    // init
    for (int b = tid; b < NBINS; b += 256) hist[b] = 0u;
    if (tid == 0) collCnt = 0;
    if (tid < DD) q[tid] = raw[row * DD + tid];
    __syncthreads();

    float qr[DD];
#pragma unroll
    for (int d = 0; d < DD; ++d) qr[d] = q[d];

    // ---- phase 1: all squared distances + histogram of float bits ----
    const float4* rv = (const float4*)raw;
    for (int j = tid; j < BN; j += 256) {
        float4 p0 = rv[j * 4 + 0];
        float4 p1 = rv[j * 4 + 1];
        float4 p2 = rv[j * 4 + 2];
        float4 p3 = rv[j * 4 + 3];
        float pr[16];
        pr[0] = p0.x; pr[1] = p0.y; pr[2] = p0.z; pr[3] = p0.w;
        pr[4] = p1.x; pr[5] = p1.y; pr[6] = p1.z; pr[7] = p1.w;
        pr[8] = p2.x; pr[9] = p2.y; pr[10] = p2.z; pr[11] = p2.w;
        pr[12] = p3.x; pr[13] = p3.y; pr[14] = p3.z; pr[15] = p3.w;
        float acc = 0.f;
#pragma unroll
        for (int d = 0; d < DD; ++d) {
            float df = qr[d] - pr[d];
            acc = fmaf(df, df, acc);
        }
        if (j == row) acc = __builtin_inff();
        d2buf[j] = acc;
        if (j != row) {
            unsigned bin = __float_as_uint(acc) >> 20;
            if (bin > NBINS - 1) bin = NBINS - 1;
            atomicAdd(&hist[bin], 1u);
        }
    }
    __syncthreads();

    // ---- phase 2: find bin containing the 25th smallest ----
    unsigned local = 0;
#pragma unroll
    for (int b = 0; b < 8; ++b) local += hist[8 * tid + b];
    scanA[tid] = local;
    __syncthreads();
    for (int off = 1; off < 256; off <<= 1) {
        unsigned add = (tid >= off) ? scanA[tid - off] : 0u;
        __syncthreads();
        scanA[tid] += add;
        __syncthreads();
    }
    {
        unsigned cumBefore = (tid == 0) ? 0u : scanA[tid - 1];
        unsigned cumIncl = scanA[tid];
        if (cumBefore < KNN && cumIncl >= KNN) {
            unsigned c = cumBefore;
            int bsel = 8 * tid + 7;
#pragma unroll
            for (int r = 0; r < 8; ++r) {
                c += hist[8 * tid + r];
                if (c >= KNN) { bsel = 8 * tid + r; break; }
            }
            binB = bsel;
        }
    }
    __syncthreads();

    // ---- phase 3: collect all candidates with bin <= binB ----
    int bstar = binB;
    for (int j = tid; j < BN; j += 256) {
        float d2 = d2buf[j];
        unsigned bin = __float_as_uint(d2) >> 20;
        if (bin > NBINS - 1) bin = NBINS - 1;
        if ((int)bin <= bstar && j != row) {
            int pos = atomicAdd(&collCnt, 1);
            if (pos < COLLCAP) { collV[pos] = d2; collI[pos] = j; }
        }
    }
    __syncthreads();
    int cnt = collCnt < COLLCAP ? collCnt : COLLCAP;

    // ---- phase 4: exact 25 smallest by (value, index) -- wave 0 ----
    if (tid < 64) {
        for (int it = 0; it < KNN; ++it) {
            unsigned long long best = 0xFFFFFFFFFFFFFFFFull;
            for (int p = tid; p < cnt; p += 64) {
                unsigned long long key =
                    (((unsigned long long)__float_as_uint(collV[p])) << 32) |
                    (unsigned)collI[p];
                if (key < best) best = key;
            }
#pragma unroll
            for (int m2 = 32; m2 >= 1; m2 >>= 1) {
                unsigned lo = (unsigned)best, hi = (unsigned)(best >> 32);
                unsigned olo = __shfl_xor(lo, m2, 64);
                unsigned ohi = __shfl_xor(hi, m2, 64);
                unsigned long long o = (((unsigned long long)ohi) << 32) | olo;
                if (o < best) best = o;
            }
            int wj = (int)(best & 0xFFFFFFFFull);
            for (int p = tid; p < cnt; p += 64)
                if (collI[p] == wj) collV[p] = __builtin_inff();
            if (tid == 0) nbr[it] = wj;
        }
    }
    __syncthreads();

    // ---- phase 5: covariance + top eigenvector for latent & raw ----
    for (int m = 0; m < 2; ++m) {
        const float* src = (m == 0) ? latent : raw;
        for (int t = tid; t < KNN * DD; t += 256) {
            int k = t >> 4, d = t & 15;
            pts[k][d] = src[nbr[k] * DD + d];
        }
        __syncthreads();
        if (tid < DD) {
            float s = 0.f;
#pragma unroll
            for (int k = 0; k < KNN; ++k) s += pts[k][tid];
            mean_s[tid] = s * (1.0f / KNN);
        }
        __syncthreads();
        for (int t = tid; t < KNN * DD; t += 256) {
            int k = t >> 4, d = t & 15;
            pts[k][d] -= mean_s[d];
        }
        __syncthreads();
        {
            int i = tid >> 4, j = tid & 15;
            float s = 0.f;
#pragma unroll
            for (int k = 0; k < KNN; ++k) s += pts[k][i] * pts[k][j];
            Cm[tid] = s;
        }
        __syncthreads();

        // 5 trace-normalized squarings: C -> C^32 (normalized)
        float* A = Cm;
        float* Bm = C2m;
        for (int sq = 0; sq < 5; ++sq) {
            if (tid == 0) {
                float tr = 0.f;
                for (int i = 0; i < DD; ++i) tr += A[i * DD + i];
                sc[0] = (tr > 0.f) ? (1.0f / tr) : 1.0f;
            }
            __syncthreads();
            float itr = sc[0];
            {
                int i = tid >> 4, j = tid & 15;
                float s = 0.f;
#pragma unroll
                for (int k = 0; k < DD; ++k) s += A[i * DD + k] * A[k * DD + j];
                Bm[tid] = s * itr * itr;
            }
            __syncthreads();
            float* tmp = A; A = Bm; Bm = tmp;
        }

        // column with largest norm
        if (tid < DD) {
            float s = 0.f;
            for (int i = 0; i < DD; ++i) { float c = A[i * DD + tid]; s += c * c; }
            ww[tid] = s;
        }
        __syncthreads();
        if (tid == 0) {
            int jm = 0; float bn = ww[0];
            for (int j = 1; j < DD; ++j) if (ww[j] > bn) { bn = ww[j]; jm = j; }
            sc[1] = __int_as_float(jm);
        }
        __syncthreads();
        int jm = __float_as_int(sc[1]);
        if (tid < DD) vv[tid] = A[tid * DD + jm];
        __syncthreads();
        // two more matvecs with A (= C^32 normalized)
        for (int pit = 0; pit < 2; ++pit) {
            if (tid < DD) {
                float s = 0.f;
                for (int j = 0; j < DD; ++j) s += A[tid * DD + j] * vv[j];
                ww[tid] = s;
            }
            __syncthreads();
            if (tid < DD) vv[tid] = ww[tid];
            __syncthreads();
        }
        if (tid == 0) {
            float n = 0.f;
            for (int i = 0; i < DD; ++i) n += vv[i] * vv[i];
            float inv = rsqrtf(fmaxf(n, 1e-30f));
            for (int i = 0; i < DD; ++i) uv[m][i] = vv[i] * inv;
        }
        __syncthreads();
    }

    if (tid == 0) {
        float dot = 0.f;
        for (int i = 0; i < DD; ++i) dot += uv[0][i] * uv[1][i];
        tsa[row] = 2.0f - 2.0f * dot * dot;   // ||uu^T - vv^T||_F^2
    }
}

// ---------------- finalize: out = recon_mean + 0.1 * tsa_mean ----------------
__global__ void finalize_kernel(const float* __restrict__ tsa,
                                const float* __restrict__ part,
                                float* __restrict__ out) {
    __shared__ float red[256];
    int tid = threadIdx.x;
    float s = 0.f;
    for (int i = tid; i < BN; i += 256) s += tsa[i];
    red[tid] = s;
    __syncthreads();
    for (int off = 128; off > 0; off >>= 1) {
        if (tid < off) red[tid] += red[tid + off];
        __syncthreads();
    }
    float tsaSum = red[0];
    __syncthreads();
    red[tid] = part[tid];
    __syncthreads();
    for (int off = 128; off > 0; off >>= 1) {
        if (tid < off) red[tid] += red[tid + off];
        __syncthreads();
    }
    if (tid == 0)
        out[0] = red[0] * (1.0f / (float)(BN * DD)) + 0.1f * (tsaSum * (1.0f / (float)BN));
}

extern "C" void kernel_launch(void* const* d_in, const int* in_sizes, int n_in,
                              void* d_out, int out_size, void* d_ws, size_t ws_size,
                              hipStream_t stream) {
    const float* outputs = (const float*)d_in[0];
    const float* targets = (const float*)d_in[1];
    const float* latent  = (const float*)d_in[2];
    const float* raw     = (const float*)d_in[3];
    float* ws   = (float*)d_ws;
    float* tsa  = ws;          // BN floats
    float* part = ws + BN;     // 256 floats

    recon_kernel<<<256, 256, 0, stream>>>(outputs, targets, part);
    tsa_kernel<<<BN, 256, 0, stream>>>(latent, raw, tsa);
    finalize_kernel<<<1, 256, 0, stream>>>(tsa, part, (float*)d_out);
}

// Round 2
// 745.177 us; speedup vs baseline: 2.1849x; 2.1849x over previous
//
#include <hip/hip_runtime.h>

#define BN 16384
#define DD 16
#define KNN 25
#define QB 8
#define NB 1024
#define CAP 672
#define CHUNK 8192

// ---------------- norms: |raw_j|^2 ----------------
__global__ void norms_kernel(const float* __restrict__ raw, float* __restrict__ nrm) {
    int j = blockIdx.x * 256 + threadIdx.x;
    if (j < BN) {
        const float4* rv = (const float4*)raw + j * 4;
        float s = 0.f;
#pragma unroll
        for (int i = 0; i < 4; ++i) {
            float4 v = rv[i];
            s = fmaf(v.x, v.x, s); s = fmaf(v.y, v.y, s);
            s = fmaf(v.z, v.z, s); s = fmaf(v.w, v.w, s);
        }
        nrm[j] = s;
    }
}

// ---------------- recon partials ----------------
__global__ void recon_kernel(const float* __restrict__ o, const float* __restrict__ t,
                             float* __restrict__ part) {
    __shared__ float red[256];
    int tid = threadIdx.x;
    int idx = blockIdx.x * 256 + tid;
    float s = 0.f;
    for (int i = idx; i < BN * DD; i += 256 * 256) {
        float d = o[i] - t[i];
        s = fmaf(d, d, s);
    }
    red[tid] = s;
    __syncthreads();
    for (int off = 128; off > 0; off >>= 1) {
        if (tid < off) red[tid] += red[tid + off];
        __syncthreads();
    }
    if (tid == 0) part[blockIdx.x] = red[0];
}

// ---------------- main: 8 rows per block ----------------
__global__ __launch_bounds__(256, 2) void tsa_kernel(const float* __restrict__ latent,
                                                     const float* __restrict__ raw,
                                                     const float* __restrict__ nrm,
                                                     float* __restrict__ tsa) {
    const int tid  = threadIdx.x;
    const int lane = tid & 63;
    const int w    = tid >> 6;
    const int row0 = blockIdx.x * QB;

    __shared__ unsigned hist[QB][NB];   // 32 KB, overlaid by eigen scratch later
    __shared__ float listV[QB][CAP];    // 21 KB
    __shared__ int   listI[QB][CAP];    // 21 KB
    __shared__ int   lcnt[QB];
    __shared__ int   bA[QB], bS[QB];
    __shared__ float qstage[QB][DD];
    __shared__ int   nbr[QB][KNN];

    for (int i = tid; i < QB * NB; i += 256) ((unsigned*)hist)[i] = 0u;
    if (tid < QB) lcnt[tid] = 0;
    if (tid < QB * DD) ((float*)qstage)[tid] = raw[row0 * DD + tid];
    __syncthreads();

    // queries -> registers (LDS broadcast reads)
    float qd[QB][DD];
    float qn[QB];
#pragma unroll
    for (int qi = 0; qi < QB; ++qi) {
        float s = 0.f;
#pragma unroll
        for (int d = 0; d < DD; ++d) {
            float v = qstage[qi][d];
            qd[qi][d] = v;
            s = fmaf(v, v, s);
        }
        qn[qi] = s;
    }

    // ---- pass 1a: chunk A, histogram only ----
    for (int j = tid; j < CHUNK; j += 256) {
        const float4* pv = (const float4*)raw + j * 4;
        float4 a = pv[0], b = pv[1], c = pv[2], e = pv[3];
        float p[16] = {a.x,a.y,a.z,a.w,b.x,b.y,b.z,b.w,c.x,c.y,c.z,c.w,e.x,e.y,e.z,e.w};
        float pn = nrm[j];
#pragma unroll
        for (int qi = 0; qi < QB; ++qi) {
            if (j == row0 + qi) continue;
            float acc = 0.f;
#pragma unroll
            for (int d = 0; d < DD; ++d) acc = fmaf(qd[qi][d], p[d], acc);
            float d2 = fmaxf(qn[qi] + pn - 2.f * acc, 0.f);
            unsigned bin = __float_as_uint(d2) >> 21;
            if (bin > NB - 1) bin = NB - 1;
            atomicAdd(&hist[qi][bin], 1u);
        }
    }
    __syncthreads();

    // ---- scan partial hist -> bA (wave w handles queries 2w, 2w+1) ----
    for (int qq = 0; qq < 2; ++qq) {
        int qi = 2 * w + qq;
        int base = lane * (NB / 64);
        unsigned part = 0;
#pragma unroll
        for (int r = 0; r < NB / 64; ++r) part += hist[qi][base + r];
        unsigned cum = part;
        for (int off = 1; off < 64; off <<= 1) {
            unsigned nn = __shfl_up(cum, off, 64);
            if (lane >= off) cum += nn;
        }
        unsigned long long mb = __ballot(cum >= KNN);
        int bl = __ffsll((long long)mb) - 1;
        if (lane == bl) {
            unsigned c = cum - part;
            int bsel = base + NB / 64 - 1;
#pragma unroll
            for (int r = 0; r < NB / 64; ++r) {
                c += hist[qi][base + r];
                if (c >= KNN) { bsel = base + r; break; }
            }
            bA[qi] = bsel;
        }
    }
    __syncthreads();
    int bar_[QB];
#pragma unroll
    for (int qi = 0; qi < QB; ++qi) bar_[qi] = bA[qi];

    // ---- pass 1b: chunk B, histogram + collect (bin <= bA) ----
    for (int j = CHUNK + tid; j < BN; j += 256) {
        const float4* pv = (const float4*)raw + j * 4;
        float4 a = pv[0], b = pv[1], c = pv[2], e = pv[3];
        float p[16] = {a.x,a.y,a.z,a.w,b.x,b.y,b.z,b.w,c.x,c.y,c.z,c.w,e.x,e.y,e.z,e.w};
        float pn = nrm[j];
#pragma unroll
        for (int qi = 0; qi < QB; ++qi) {
            if (j == row0 + qi) continue;
            float acc = 0.f;
#pragma unroll
            for (int d = 0; d < DD; ++d) acc = fmaf(qd[qi][d], p[d], acc);
            float d2 = fmaxf(qn[qi] + pn - 2.f * acc, 0.f);
            unsigned bin = __float_as_uint(d2) >> 21;
            if (bin > NB - 1) bin = NB - 1;
            atomicAdd(&hist[qi][bin], 1u);
            if ((int)bin <= bar_[qi]) {
                int pos = atomicAdd(&lcnt[qi], 1);
                if (pos < CAP) { listV[qi][pos] = d2; listI[qi][pos] = j; }
            }
        }
    }
    __syncthreads();

    // ---- scan full hist -> bS ----
    for (int qq = 0; qq < 2; ++qq) {
        int qi = 2 * w + qq;
        int base = lane * (NB / 64);
        unsigned part = 0;
#pragma unroll
        for (int r = 0; r < NB / 64; ++r) part += hist[qi][base + r];
        unsigned cum = part;
        for (int off = 1; off < 64; off <<= 1) {
            unsigned nn = __shfl_up(cum, off, 64);
            if (lane >= off) cum += nn;
        }
        unsigned long long mb = __ballot(cum >= KNN);
        int bl = __ffsll((long long)mb) - 1;
        if (lane == bl) {
            unsigned c = cum - part;
            int bsel = base + NB / 64 - 1;
#pragma unroll
            for (int r = 0; r < NB / 64; ++r) {
                c += hist[qi][base + r];
                if (c >= KNN) { bsel = base + r; break; }
            }
            bS[qi] = bsel;
        }
    }
    __syncthreads();
    int bsr_[QB];
#pragma unroll
    for (int qi = 0; qi < QB; ++qi) bsr_[qi] = bS[qi];

    // ---- pass 2: chunk A recompute, collect (bin <= bS) ----
    for (int j = tid; j < CHUNK; j += 256) {
        const float4* pv = (const float4*)raw + j * 4;
        float4 a = pv[0], b = pv[1], c = pv[2], e = pv[3];
        float p[16] = {a.x,a.y,a.z,a.w,b.x,b.y,b.z,b.w,c.x,c.y,c.z,c.w,e.x,e.y,e.z,e.w};
        float pn = nrm[j];
#pragma unroll
        for (int qi = 0; qi < QB; ++qi) {
            if (j == row0 + qi) continue;
            float acc = 0.f;
#pragma unroll
            for (int d = 0; d < DD; ++d) acc = fmaf(qd[qi][d], p[d], acc);
            float d2 = fmaxf(qn[qi] + pn - 2.f * acc, 0.f);
            unsigned bin = __float_as_uint(d2) >> 21;
            if (bin > NB - 1) bin = NB - 1;
            if ((int)bin <= bsr_[qi]) {
                int pos = atomicAdd(&lcnt[qi], 1);
                if (pos < CAP) { listV[qi][pos] = d2; listI[qi][pos] = j; }
            }
        }
    }
    __syncthreads();

    // ---- exact top-25 per query (wave-local, (d2,idx) tie-break) ----
    for (int qq = 0; qq < 2; ++qq) {
        int qi = 2 * w + qq;
        int cnt = lcnt[qi]; if (cnt > CAP) cnt = CAP;
        for (int it = 0; it < KNN; ++it) {
            unsigned long long best = ~0ull;
            for (int e = lane; e < cnt; e += 64) {
                unsigned long long key =
                    (((unsigned long long)__float_as_uint(listV[qi][e])) << 32) |
                    (unsigned)listI[qi][e];
                if (key < best) best = key;
            }
#pragma unroll
            for (int m2 = 32; m2 >= 1; m2 >>= 1) {
                unsigned lo = (unsigned)best, hi = (unsigned)(best >> 32);
                unsigned olo = __shfl_xor(lo, m2, 64);
                unsigned ohi = __shfl_xor(hi, m2, 64);
                unsigned long long ob = (((unsigned long long)ohi) << 32) | olo;
                if (ob < best) best = ob;
            }
            int wj = (int)(best & 0xffffffffu);
            for (int e = lane; e < cnt; e += 64)
                if (listI[qi][e] == wj) listV[qi][e] = __builtin_inff();
            if (lane == 0) nbr[qi][it] = wj;
        }
    }
    __syncthreads();

    // ---- eigen phase: wave w owns rows 2w, 2w+1; scratch overlays hist ----
    float* ws  = (float*)hist + w * 1024;
    float* pts = ws;            // 25*16 = 400
    float* Am0 = ws + 400;      // 256
    float* Bm0 = ws + 656;      // 256
    float* vv  = ws + 912;      // 16
    float* mn  = ws + 928;      // 16
    float* uv  = ws + 944;      // 32

    for (int rr = 0; rr < 2; ++rr) {
        int qi = 2 * w + rr;
        for (int m = 0; m < 2; ++m) {
            const float* src = (m == 0) ? latent : raw;
            for (int e = lane; e < KNN * DD; e += 64)
                pts[e] = src[nbr[qi][e >> 4] * DD + (e & 15)];
            __syncthreads();
            if (lane < DD) {
                float s = 0.f;
#pragma unroll
                for (int k = 0; k < KNN; ++k) s += pts[k * DD + lane];
                mn[lane] = s * (1.0f / KNN);
            }
            __syncthreads();
            for (int e = lane; e < KNN * DD; e += 64) pts[e] -= mn[e & 15];
            __syncthreads();
#pragma unroll
            for (int s4 = 0; s4 < 4; ++s4) {
                int e = lane + 64 * s4;
                int i = e >> 4, jj = e & 15;
                float s = 0.f;
#pragma unroll
                for (int k = 0; k < KNN; ++k) s = fmaf(pts[k * DD + i], pts[k * DD + jj], s);
                Am0[e] = s;
            }
            __syncthreads();

            float* A = Am0;
            float* B = Bm0;
            for (int sq = 0; sq < 5; ++sq) {
                float t = (lane < DD) ? A[lane * 17] : 0.f;
#pragma unroll
                for (int off = 32; off >= 1; off >>= 1) t += __shfl_xor(t, off, 64);
                float itr = (t > 0.f) ? (1.0f / t) : 1.0f;
#pragma unroll
                for (int s4 = 0; s4 < 4; ++s4) {
                    int e = lane + 64 * s4;
                    int i = e >> 4, jj = e & 15;
                    float s = 0.f;
#pragma unroll
                    for (int k = 0; k < DD; ++k) s = fmaf(A[i * DD + k], A[k * DD + jj], s);
                    B[e] = s * itr * itr;
                }
                __syncthreads();
                float* tmp = A; A = B; B = tmp;
            }

            // column with largest norm (tie: lower j)
            float cn = -1.f;
            if (lane < DD) {
                cn = 0.f;
#pragma unroll
                for (int i = 0; i < DD; ++i) { float c = A[i * DD + lane]; cn = fmaf(c, c, cn); }
            }
            int bj = lane & 15;
#pragma unroll
            for (int off = 32; off >= 1; off >>= 1) {
                float on = __shfl_xor(cn, off, 64);
                int   oj = __shfl_xor(bj, off, 64);
                if (on > cn || (on == cn && oj < bj)) { cn = on; bj = oj; }
            }
            if (lane < DD) vv[lane] = A[lane * DD + bj];
            __syncthreads();

            for (int pit = 0; pit < 2; ++pit) {
                float s = 0.f;
                if (lane < DD) {
#pragma unroll
                    for (int jj = 0; jj < DD; ++jj) s = fmaf(A[lane * DD + jj], vv[jj], s);
                }
                __syncthreads();
                if (lane < DD) vv[lane] = s;
                __syncthreads();
            }

            float nv = (lane < DD) ? vv[lane] * vv[lane] : 0.f;
#pragma unroll
            for (int off = 32; off >= 1; off >>= 1) nv += __shfl_xor(nv, off, 64);
            float inv = rsqrtf(fmaxf(nv, 1e-30f));
            if (lane < DD) uv[m * DD + lane] = vv[lane] * inv;
            __syncthreads();
        }
        float dt = (lane < DD) ? uv[lane] * uv[DD + lane] : 0.f;
#pragma unroll
        for (int off = 32; off >= 1; off >>= 1) dt += __shfl_xor(dt, off, 64);
        if (lane == 0) tsa[row0 + qi] = 2.0f - 2.0f * dt * dt;
        __syncthreads();
    }
}

// ---------------- finalize ----------------
__global__ void finalize_kernel(const float* __restrict__ tsa,
                                const float* __restrict__ part,
                                float* __restrict__ out) {
    __shared__ float red[256];
    int tid = threadIdx.x;
    float s = 0.f;
    for (int i = tid; i < BN; i += 256) s += tsa[i];
    red[tid] = s;
    __syncthreads();
    for (int off = 128; off > 0; off >>= 1) {
        if (tid < off) red[tid] += red[tid + off];
        __syncthreads();
    }
    float tsaSum = red[0];
    __syncthreads();
    red[tid] = part[tid];
    __syncthreads();
    for (int off = 128; off > 0; off >>= 1) {
        if (tid < off) red[tid] += red[tid + off];
        __syncthreads();
    }
    if (tid == 0)
        out[0] = red[0] * (1.0f / (float)(BN * DD)) + 0.1f * (tsaSum * (1.0f / (float)BN));
}

extern "C" void kernel_launch(void* const* d_in, const int* in_sizes, int n_in,
                              void* d_out, int out_size, void* d_ws, size_t ws_size,
                              hipStream_t stream) {
    const float* outputs = (const float*)d_in[0];
    const float* targets = (const float*)d_in[1];
    const float* latent  = (const float*)d_in[2];
    const float* raw     = (const float*)d_in[3];
    float* ws_f = (float*)d_ws;
    float* tsa  = ws_f;            // BN
    float* part = ws_f + BN;       // 256
    float* nrm  = ws_f + BN + 256; // BN

    norms_kernel<<<BN / 256, 256, 0, stream>>>(raw, nrm);
    recon_kernel<<<256, 256, 0, stream>>>(outputs, targets, part);
    tsa_kernel<<<BN / QB, 256, 0, stream>>>(latent, raw, nrm, tsa);
    finalize_kernel<<<1, 256, 0, stream>>>(tsa, part, (float*)d_out);
}